// Round 13
// baseline (162.906 us; speedup 1.0000x reference)
//
#include <hip/hip_runtime.h>
#include <hip/hip_bf16.h>
#include <stdint.h>

typedef __bf16 bf16_t;
typedef __bf16 bf16x8 __attribute__((ext_vector_type(8)));
typedef float  f32x4  __attribute__((ext_vector_type(4)));

#define DIM    1024
#define NTOK   4096
#define NB     8
#define ROWS   (NB*NTOK)   // 32768
#define QKVC   384
#define INNER  128

// global -> LDS direct copy, 16B per lane (dest = wave-uniform base + lane*16)
#define GLD16(g, l) __builtin_amdgcn_global_load_lds( \
    (const __attribute__((address_space(1))) void*)(g), \
    (__attribute__((address_space(3))) void*)(l), 16, 0, 0)

#define VMCNT(n) asm volatile("s_waitcnt vmcnt(" #n ")" ::: "memory")

// workspace offsets (bytes)
#define OFF_WQ    131072u      // 384*1024 bf16   (768 KB)
#define OFF_QKV   1048576u     // 32768*384 bf16  (24 MB)
#define OFF_STATS 26214400u    // 512 chunks * 2304 f32
#define OFF_ATTN  30932992u    // 8*8*16*16 f32
#define OFF_WEFF  30998528u    // 8*1024*128 bf16

// ---------- kernel 0: w_qkv * norm_weight -> bf16 ----------
__global__ __launch_bounds__(256) void k_wconv(const float* __restrict__ wq,
    const float* __restrict__ nw, bf16_t* __restrict__ wqb)
{
    int o = blockIdx.x;            // 384 rows
    int c = threadIdx.x * 4;
    float4 wv = *reinterpret_cast<const float4*>(wq + (size_t)o*DIM + c);
    float4 nv = *reinterpret_cast<const float4*>(nw + c);
    bf16_t* dst = wqb + (size_t)o*DIM + c;
    dst[0]=(bf16_t)(wv.x*nv.x); dst[1]=(bf16_t)(wv.y*nv.y);
    dst[2]=(bf16_t)(wv.z*nv.z); dst[3]=(bf16_t)(wv.w*nv.w);
}

// ---------- kernel 1: FUSED RMSNorm + QKV GEMM, A-direct-from-global ----------
// R8..R12 lesson: any schedule with A in the global->LDS->barrier contract pins
// at ~330 TF/CU-step (MfmaUtil ~11%) — barrier makes A latency additive.
// Here A never touches LDS: the 16x16x32 A-fragment (lane lr=row, lg=k-slice)
// is loaded per-lane from x (8 fp32 = one 32B chunk of a 128B row-line),
// converted in-reg, MFMA'd. Only B (24KB/step, L2-resident weight) is LDS-
// staged (GLD16, dbuf, one raw barrier/step; issue order B-then-A so top-of-
// step vmcnt(0) is the only wait, with a full step in flight).
// Block: 512 thr = 8 waves (2M x 4N), 128 rows x all 384 cols; wave 64x96.
__global__ __launch_bounds__(512) void k_qkv_gemm(const float* __restrict__ x,
    const bf16_t* __restrict__ wqb, bf16_t* __restrict__ qkv)
{
    __shared__ bf16_t Bl[2][384*32];   // 2 x 24 KB
    __shared__ float srow[128];
    int mt = blockIdx.x;               // 256 blocks
    int row0 = mt*128;
    int t = threadIdx.x;
    int lane = t & 63, lr = lane & 15, lg = lane >> 4;
    int w = t >> 6, wm = w >> 2, wn = w & 3;   // 2M x 4N

    // A direct: lane covers rows wm*64 + mi*16 + lr, k-elems lg*8..lg*8+7
    const float* abase = x + (size_t)(row0 + wm*64 + lr)*DIM + lg*8;

    // B staging: round j: row j*128 + (t>>2), dest slot t&3 (linear);
    // source k-slot inverse-swizzled by sigma(row) = (row>>1)&3 = (t>>3)&3.
    int sgB = (t & 3) ^ ((t >> 3) & 3);
    const bf16_t* bsrc = wqb + (size_t)(t >> 2)*DIM + sgB*8;

    int kbB = (lg ^ ((lr >> 1) & 3)) * 8;   // B read-side physical slot (elems)

    float4 pA[8];                      // raw A prefetch (static-indexed)
    bf16x8 af[4];
    float ssq[4] = {0.f, 0.f, 0.f, 0.f};
    f32x4 acc[4][6] = {};

#define STAGEB(buf, kt) do {                                              \
        _Pragma("unroll")                                                 \
        for (int _j = 0; _j < 3; _j++)                                    \
            GLD16(bsrc + (size_t)(_j*128)*DIM + (kt)*32,                  \
                  &Bl[buf][_j*4096 + t*8]);                               \
    } while (0)

#define LOADA(kt) do {                                                    \
        _Pragma("unroll")                                                 \
        for (int _mi = 0; _mi < 4; _mi++) {                               \
            const float4* _p = reinterpret_cast<const float4*>(           \
                abase + (size_t)(_mi*16)*DIM + (kt)*32);                  \
            pA[_mi*2] = _p[0]; pA[_mi*2+1] = _p[1];                       \
        }                                                                 \
    } while (0)

#define CVTA() do {                                                       \
        _Pragma("unroll")                                                 \
        for (int _mi = 0; _mi < 4; _mi++) {                               \
            float4 _a = pA[_mi*2], _b = pA[_mi*2+1];                      \
            ssq[_mi] += _a.x*_a.x + _a.y*_a.y + _a.z*_a.z + _a.w*_a.w     \
                      + _b.x*_b.x + _b.y*_b.y + _b.z*_b.z + _b.w*_b.w;    \
            bf16x8 _v;                                                    \
            _v[0]=(bf16_t)_a.x; _v[1]=(bf16_t)_a.y; _v[2]=(bf16_t)_a.z;   \
            _v[3]=(bf16_t)_a.w; _v[4]=(bf16_t)_b.x; _v[5]=(bf16_t)_b.y;   \
            _v[6]=(bf16_t)_b.z; _v[7]=(bf16_t)_b.w;                       \
            af[_mi] = _v;                                                 \
        }                                                                 \
    } while (0)

    // prologue: B(0) first (oldest), then A(0)
    STAGEB(0, 0);
    LOADA(0);

    for (int kt = 0; kt < 32; kt++) {
        int cur = kt & 1;
        VMCNT(0);                      // B(kt)+A(kt) landed (this wave)
        __builtin_amdgcn_s_barrier();  // all waves' B(kt) in LDS; prev reads done
        if (kt < 31) STAGEB(cur ^ 1, kt + 1);   // issue B(t+1) early (oldest)
        CVTA();                        // extract A(kt) before pA overwrite
        if (kt < 31) LOADA(kt + 1);    // issue A(t+1)
        bf16x8 bfr[6];
        #pragma unroll
        for (int ni = 0; ni < 6; ni++)
            bfr[ni] = *reinterpret_cast<const bf16x8*>(
                &Bl[cur][(wn*96 + ni*16 + lr)*32 + kbB]);
        #pragma unroll
        for (int mi = 0; mi < 4; mi++)
            #pragma unroll
            for (int ni = 0; ni < 6; ni++)
                acc[mi][ni] = __builtin_amdgcn_mfma_f32_16x16x32_bf16(
                    af[mi], bfr[ni], acc[mi][ni], 0, 0, 0);
    }
#undef STAGEB
#undef LOADA
#undef CVTA

    // ssq: lanes (lr, lg) hold k-slice partials; sum over the 4 lg copies
    #pragma unroll
    for (int mi = 0; mi < 4; mi++) {
        ssq[mi] += __shfl_xor(ssq[mi], 16, 64);
        ssq[mi] += __shfl_xor(ssq[mi], 32, 64);
    }
    if (wn == 0 && lane < 16) {
        #pragma unroll
        for (int mi = 0; mi < 4; mi++)
            srow[wm*64 + mi*16 + lane] = rsqrtf(ssq[mi]*(1.0f/DIM) + 1e-6f);
    }
    __syncthreads();

    #pragma unroll
    for (int mi = 0; mi < 4; mi++)
        #pragma unroll
        for (int ni = 0; ni < 6; ni++) {
            int col_g = wn*96 + ni*16 + lr;
            #pragma unroll
            for (int rr = 0; rr < 4; rr++) {
                int rloc = wm*64 + mi*16 + lg*4 + rr;
                qkv[(size_t)(row0 + rloc)*QKVC + col_g] =
                    (bf16_t)(acc[mi][ni][rr] * srow[rloc]);
            }
        }
}

// ---------- kernel 2: per-(b,chunk) Gram + sumsq partials ----------
__global__ __launch_bounds__(256) void k_stats(const bf16_t* __restrict__ qkv,
    float* __restrict__ stats)
{
    __shared__ bf16_t qk[64*264];   // 64 tokens x 256 (q,k cols) + pad 8
    int bid = blockIdx.x;           // 512 = 8b * 64ch
    int b = bid >> 6, ch = bid & 63;
    int t = threadIdx.x;
    #pragma unroll
    for (int rd = 0; rd < 8; rd++) {
        int tok = (t >> 5) + 8*rd;
        int c8  = (t & 31) * 8;     // cols 0..255 = q,k
        *reinterpret_cast<uint4*>(&qk[tok*264 + c8]) =
            *reinterpret_cast<const uint4*>(
                qkv + ((size_t)b*NTOK + ch*64 + tok)*QKVC + c8);
    }
    __syncthreads();
    int h = t >> 5, s = t & 31, i0 = (s >> 4)*8, j = s & 15;
    float gram[8] = {}, qsq[8] = {}, ksq = 0.f;
    for (int tok = 0; tok < 64; tok++) {
        bf16x8 q8 = *reinterpret_cast<const bf16x8*>(&qk[tok*264 + h*16 + i0]);
        float kf = (float)qk[tok*264 + 128 + h*16 + j];
        ksq += kf*kf;
        #pragma unroll
        for (int m = 0; m < 8; m++) {
            float qf = (float)q8[m];
            gram[m] += qf*kf;
            qsq[m]  += qf*qf;
        }
    }
    float* base = stats + ((size_t)(b*64 + ch)*8 + h)*288;
    #pragma unroll
    for (int m = 0; m < 8; m++) base[(i0 + m)*16 + j] = gram[m];
    if (j == 0) {
        #pragma unroll
        for (int m = 0; m < 8; m++) base[256 + i0 + m] = qsq[m];
    }
    if (s < 16) base[272 + j] = ksq;
}

// ---------- kernel 3: reduce partials, l2-normalize, temperature, softmax ----------
__global__ __launch_bounds__(256) void k_attn(const float* __restrict__ stats,
    const float* __restrict__ temp, float* __restrict__ attn)
{
    int bid = blockIdx.x;           // 64 = 8b * 8h
    int b = bid >> 3, h = bid & 7;
    int t = threadIdx.x, i = t >> 4, j = t & 15;
    float gsum = 0.f, qs = 0.f, ks = 0.f;
    for (int ch = 0; ch < 64; ch++) {
        const float* base = stats + ((size_t)(b*64 + ch)*8 + h)*288;
        gsum += base[i*16 + j];
        qs   += base[256 + i];
        ks   += base[272 + j];
    }
    float et  = expf(temp[h]);
    float sim = gsum * et / (fmaxf(sqrtf(qs), 1e-12f) * fmaxf(sqrtf(ks), 1e-12f));
    float m = sim;
    #pragma unroll
    for (int d = 1; d < 16; d <<= 1) m = fmaxf(m, __shfl_xor(m, d, 16));
    float e = expf(sim - m);
    float ssum = e;
    #pragma unroll
    for (int d = 1; d < 16; d <<= 1) ssum += __shfl_xor(ssum, d, 16);
    attn[((size_t)(b*8 + h)*16 + i)*16 + j] = e / ssum;
}

// ---------- kernel 4: w_eff[b][o][c] = sum_i w_out[o][h*16+i]*attn[b][h][i][j] ----------
__global__ __launch_bounds__(256) void k_weff(const float* __restrict__ attn,
    const float* __restrict__ wout, bf16_t* __restrict__ weff)
{
    __shared__ float at[2048];
    int bid = blockIdx.x;           // 256 = 8b * 32
    int b = bid >> 5, ob = (bid & 31)*32;
    int t = threadIdx.x;
    #pragma unroll
    for (int r = 0; r < 8; r++) at[t + 256*r] = attn[(size_t)b*2048 + t + 256*r];
    __syncthreads();
    int c = t & 127, h = c >> 4, j = c & 15, oo = (t >> 7)*16;
    #pragma unroll
    for (int m = 0; m < 16; m++) {
        int o = ob + oo + m;
        float acc = 0.f;
        #pragma unroll
        for (int i2 = 0; i2 < 16; i2++)
            acc += wout[(size_t)o*INNER + h*16 + i2] * at[(h*16 + i2)*16 + j];
        weff[((size_t)b*DIM + o)*INNER + c] = (bf16_t)acc;
    }
}

// ---------- kernel 5: output GEMM  per b: (4096x128)x(128x1024), fp32 out ----------
__global__ __launch_bounds__(256) void k_out_gemm(const bf16_t* __restrict__ qkv,
    const bf16_t* __restrict__ weff, float* __restrict__ out)
{
    __shared__ bf16_t Al[128*136];
    __shared__ bf16_t Bl[128*136];
    int bid = blockIdx.x;           // 2048 = 8b * 32mt * 8nt
    int b = bid >> 8, rem = bid & 255;
    int mt = rem >> 3, nt = rem & 7;
    int tok0 = mt*128, o0 = nt*128;
    int t = threadIdx.x;
    #pragma unroll
    for (int rd = 0; rd < 8; rd++) {
        int r  = (t >> 4) + 16*rd;
        int c8 = (t & 15) * 8;
        *reinterpret_cast<uint4*>(&Al[r*136 + c8]) =
            *reinterpret_cast<const uint4*>(
                qkv + ((size_t)b*NTOK + tok0 + r)*QKVC + 256 + c8);   // v cols
        *reinterpret_cast<uint4*>(&Bl[r*136 + c8]) =
            *reinterpret_cast<const uint4*>(
                weff + ((size_t)b*DIM + o0 + r)*INNER + c8);
    }
    __syncthreads();
    int w = t >> 6, lane = t & 63, lr = lane & 15, lg = lane >> 4;
    int wr = (w & 1)*64, wc = (w >> 1)*64;
    f32x4 acc[4][4] = {};
    #pragma unroll
    for (int kk = 0; kk < 4; kk++) {
        int kb = kk*32 + lg*8;
        bf16x8 af[4], bfr[4];
        #pragma unroll
        for (int mi = 0; mi < 4; mi++)
            af[mi] = *reinterpret_cast<const bf16x8*>(&Al[(wr + mi*16 + lr)*136 + kb]);
        #pragma unroll
        for (int ni = 0; ni < 4; ni++)
            bfr[ni] = *reinterpret_cast<const bf16x8*>(&Bl[(wc + ni*16 + lr)*136 + kb]);
        #pragma unroll
        for (int mi = 0; mi < 4; mi++)
            #pragma unroll
            for (int ni = 0; ni < 4; ni++)
                acc[mi][ni] = __builtin_amdgcn_mfma_f32_16x16x32_bf16(
                    af[mi], bfr[ni], acc[mi][ni], 0, 0, 0);
    }
    #pragma unroll
    for (int mi = 0; mi < 4; mi++)
        #pragma unroll
        for (int ni = 0; ni < 4; ni++) {
            int col_g = o0 + wc + ni*16 + lr;
            #pragma unroll
            for (int r = 0; r < 4; r++) {
                int row_g = tok0 + wr + mi*16 + lg*4 + r;
                out[((size_t)b*NTOK + row_g)*DIM + col_g] = acc[mi][ni][r];
            }
        }
}

extern "C" void kernel_launch(void* const* d_in, const int* in_sizes, int n_in,
                              void* d_out, int out_size, void* d_ws, size_t ws_size,
                              hipStream_t stream)
{
    const float* x    = (const float*)d_in[0];   // 8*4096*1024
    const float* nw   = (const float*)d_in[1];   // 1024
    const float* wq   = (const float*)d_in[2];   // 384*1024
    const float* temp = (const float*)d_in[3];   // 8
    const float* wout = (const float*)d_in[4];   // 1024*128
    float* out = (float*)d_out;

    char* ws = (char*)d_ws;
    bf16_t* wqb   = (bf16_t*)(ws + OFF_WQ);
    bf16_t* qkv   = (bf16_t*)(ws + OFF_QKV);
    float*  stats = (float*)(ws + OFF_STATS);
    float*  attn  = (float*)(ws + OFF_ATTN);
    bf16_t* weff  = (bf16_t*)(ws + OFF_WEFF);

    k_wconv    <<<384,  256, 0, stream>>>(wq, nw, wqb);
    k_qkv_gemm <<<256,  512, 0, stream>>>(x, wqb, qkv);
    k_stats    <<<512,  256, 0, stream>>>(qkv, stats);
    k_attn     <<<64,   256, 0, stream>>>(stats, temp, attn);
    k_weff     <<<256,  256, 0, stream>>>(attn, wout, weff);
    k_out_gemm <<<2048, 256, 0, stream>>>(qkv, weff, out);
}

// Round 14
// 123.980 us; speedup vs baseline: 1.3140x; 1.3140x over previous
//
#include <hip/hip_runtime.h>
#include <hip/hip_bf16.h>
#include <stdint.h>

typedef __bf16 bf16_t;
typedef __bf16 bf16x8 __attribute__((ext_vector_type(8)));
typedef float  f32x4  __attribute__((ext_vector_type(4)));

#define DIM    1024
#define NTOK   4096
#define NB     8
#define ROWS   (NB*NTOK)   // 32768
#define QKVC   384
#define INNER  128

// global -> LDS direct copy, 16B per lane (dest = wave-uniform base + lane*16)
#define GLD16(g, l) __builtin_amdgcn_global_load_lds( \
    (const __attribute__((address_space(1))) void*)(g), \
    (__attribute__((address_space(3))) void*)(l), 16, 0, 0)

// workspace offsets (bytes)
#define OFF_WQ    131072u      // 384*1024 bf16   (768 KB)
#define OFF_QKV   1048576u     // 32768*384 bf16  (24 MB)
#define OFF_STATS 26214400u    // 512 chunks * 2304 f32
#define OFF_ATTN  30932992u    // 8*8*16*16 f32
#define OFF_WEFF  30998528u    // 8*1024*128 bf16

// ---------- kernel 0: w_qkv * norm_weight -> bf16 ----------
__global__ __launch_bounds__(256) void k_wconv(const float* __restrict__ wq,
    const float* __restrict__ nw, bf16_t* __restrict__ wqb)
{
    int o = blockIdx.x;            // 384 rows
    int c = threadIdx.x * 4;
    float4 wv = *reinterpret_cast<const float4*>(wq + (size_t)o*DIM + c);
    float4 nv = *reinterpret_cast<const float4*>(nw + c);
    bf16_t* dst = wqb + (size_t)o*DIM + c;
    dst[0]=(bf16_t)(wv.x*nv.x); dst[1]=(bf16_t)(wv.y*nv.y);
    dst[2]=(bf16_t)(wv.z*nv.z); dst[3]=(bf16_t)(wv.w*nv.w);
}

// ---------- kernel 1: FUSED RMSNorm + QKV GEMM — exact m97 structure ----------
// m97 invariants restored: BOTH operands pure GLD16 -> LDS (no reg staging, no
// VALU in the staging window), single buffer, plain 2-syncthreads loop, 128^2
// tile, BK=64, 256 thr, 3 blocks/CU (48.5 KB LDS). Twist for fusion: A staged
// as RAW fp32 (GLD16 is a pure copy); fp32->bf16 convert + ssq happen on the
// READ side, inside the compute phase. XCD-bijective trio swizzle shares the
// x panel via L2. Swizzles (rule #21, both sides): A LDS[r][p]=x[r][p^(r&15)]
// (16 slots), B LDS[r][p]=w[r][p^(r&7)] (8 slots); all reads exactly-2-way.
__global__ __launch_bounds__(256) void k_qkv_gemm(const float* __restrict__ x,
    const bf16_t* __restrict__ wqb, bf16_t* __restrict__ qkv)
{
    __shared__ float  Af[128*64];      // 32 KB (fp32 A tile)
    __shared__ bf16_t Bl[128*64];      // 16 KB
    __shared__ float srow[128];
    int b0 = blockIdx.x;               // 768 = 256mt x 3nt
    int orig = (b0 & 7)*96 + (b0 >> 3);   // bijective XCD swizzle (768%8==0)
    int mt = orig / 3, nt = orig % 3;
    int row0 = mt*128, col0 = nt*128;
    int t = threadIdx.x;
    int lane = t & 63, lr = lane & 15, lg = lane >> 4;
    int w = t >> 6, wm = w >> 1, wn = w & 1;   // 2x2 wave grid, 64x64/wave

    // A staging: 8 GLD16/thread; instr j: row j*16+(t>>4), dest slot t&15,
    // source k-slot (t&15)^((t>>4)&15)  [row&15 == (t>>4)&15]
    int sA = (t & 15) ^ ((t >> 4) & 15);
    const float* asrc = x + (size_t)(row0 + (t >> 4))*DIM + sA*4;
    // B staging: 4 GLD16/thread; instr j: row col0+j*32+(t>>3), dest slot t&7,
    // source k-slot (t&7)^((t>>3)&7)
    int sB = (t & 7) ^ ((t >> 3) & 7);
    const bf16_t* bsrc = wqb + (size_t)(col0 + (t >> 3))*DIM + sB*8;

    float ssq[4] = {0.f, 0.f, 0.f, 0.f};
    f32x4 acc[4][4] = {};

    for (int kt = 0; kt < 16; kt++) {
        __syncthreads();               // prev compute done before overwrite
        #pragma unroll
        for (int j = 0; j < 8; j++)
            GLD16(asrc + (size_t)(j*16)*DIM + kt*64, &Af[j*1024 + t*4]);
        #pragma unroll
        for (int j = 0; j < 4; j++)
            GLD16(bsrc + (size_t)(j*32)*DIM + kt*64, &Bl[j*2048 + t*8]);
        __syncthreads();               // staging drained (vmcnt0 in syncthreads)
        #pragma unroll
        for (int kk = 0; kk < 2; kk++) {
            bf16x8 af[4], bfr[4];
            #pragma unroll
            for (int mi = 0; mi < 4; mi++) {
                int rowA = wm*64 + mi*16 + lr;          // rowA&15 == lr
                int p0 = (kk*8 + lg*2)     ^ lr;        // phys 16B-slot
                int p1 = (kk*8 + lg*2 + 1) ^ lr;
                float4 u0 = *reinterpret_cast<const float4*>(&Af[rowA*64 + p0*4]);
                float4 u1 = *reinterpret_cast<const float4*>(&Af[rowA*64 + p1*4]);
                if (wn == 0)                            // wave-uniform branch
                    ssq[mi] += u0.x*u0.x + u0.y*u0.y + u0.z*u0.z + u0.w*u0.w
                             + u1.x*u1.x + u1.y*u1.y + u1.z*u1.z + u1.w*u1.w;
                bf16x8 v;
                v[0]=(bf16_t)u0.x; v[1]=(bf16_t)u0.y; v[2]=(bf16_t)u0.z;
                v[3]=(bf16_t)u0.w; v[4]=(bf16_t)u1.x; v[5]=(bf16_t)u1.y;
                v[6]=(bf16_t)u1.z; v[7]=(bf16_t)u1.w;
                af[mi] = v;
            }
            #pragma unroll
            for (int ni = 0; ni < 4; ni++) {
                int rowB = wn*64 + ni*16 + lr;          // rowB&7 == lr&7
                int pb = ((kk*4 + lg) ^ (lr & 7));
                bfr[ni] = *reinterpret_cast<const bf16x8*>(&Bl[rowB*64 + pb*8]);
            }
            #pragma unroll
            for (int mi = 0; mi < 4; mi++)
                #pragma unroll
                for (int ni = 0; ni < 4; ni++)
                    acc[mi][ni] = __builtin_amdgcn_mfma_f32_16x16x32_bf16(
                        af[mi], bfr[ni], acc[mi][ni], 0, 0, 0);
        }
    }

    // ssq: (kt,kk,lg) partitioned k exactly once; sum the 4 lg copies
    #pragma unroll
    for (int mi = 0; mi < 4; mi++) {
        ssq[mi] += __shfl_xor(ssq[mi], 16, 64);
        ssq[mi] += __shfl_xor(ssq[mi], 32, 64);
    }
    if (wn == 0 && lane < 16) {
        #pragma unroll
        for (int mi = 0; mi < 4; mi++)
            srow[wm*64 + mi*16 + lane] = rsqrtf(ssq[mi]*(1.0f/DIM) + 1e-6f);
    }
    __syncthreads();

    #pragma unroll
    for (int mi = 0; mi < 4; mi++)
        #pragma unroll
        for (int ni = 0; ni < 4; ni++) {
            int col_g = col0 + wn*64 + ni*16 + lr;
            #pragma unroll
            for (int rr = 0; rr < 4; rr++) {
                int rloc = wm*64 + mi*16 + lg*4 + rr;
                qkv[(size_t)(row0 + rloc)*QKVC + col_g] =
                    (bf16_t)(acc[mi][ni][rr] * srow[rloc]);
            }
        }
}

// ---------- kernel 2: per-(b,chunk) Gram + sumsq partials ----------
__global__ __launch_bounds__(256) void k_stats(const bf16_t* __restrict__ qkv,
    float* __restrict__ stats)
{
    __shared__ bf16_t qk[64*264];   // 64 tokens x 256 (q,k cols) + pad 8
    int bid = blockIdx.x;           // 512 = 8b * 64ch
    int b = bid >> 6, ch = bid & 63;
    int t = threadIdx.x;
    #pragma unroll
    for (int rd = 0; rd < 8; rd++) {
        int tok = (t >> 5) + 8*rd;
        int c8  = (t & 31) * 8;     // cols 0..255 = q,k
        *reinterpret_cast<uint4*>(&qk[tok*264 + c8]) =
            *reinterpret_cast<const uint4*>(
                qkv + ((size_t)b*NTOK + ch*64 + tok)*QKVC + c8);
    }
    __syncthreads();
    int h = t >> 5, s = t & 31, i0 = (s >> 4)*8, j = s & 15;
    float gram[8] = {}, qsq[8] = {}, ksq = 0.f;
    for (int tok = 0; tok < 64; tok++) {
        bf16x8 q8 = *reinterpret_cast<const bf16x8*>(&qk[tok*264 + h*16 + i0]);
        float kf = (float)qk[tok*264 + 128 + h*16 + j];
        ksq += kf*kf;
        #pragma unroll
        for (int m = 0; m < 8; m++) {
            float qf = (float)q8[m];
            gram[m] += qf*kf;
            qsq[m]  += qf*qf;
        }
    }
    float* base = stats + ((size_t)(b*64 + ch)*8 + h)*288;
    #pragma unroll
    for (int m = 0; m < 8; m++) base[(i0 + m)*16 + j] = gram[m];
    if (j == 0) {
        #pragma unroll
        for (int m = 0; m < 8; m++) base[256 + i0 + m] = qsq[m];
    }
    if (s < 16) base[272 + j] = ksq;
}

// ---------- kernel 3: reduce partials, l2-normalize, temperature, softmax ----------
__global__ __launch_bounds__(256) void k_attn(const float* __restrict__ stats,
    const float* __restrict__ temp, float* __restrict__ attn)
{
    int bid = blockIdx.x;           // 64 = 8b * 8h
    int b = bid >> 3, h = bid & 7;
    int t = threadIdx.x, i = t >> 4, j = t & 15;
    float gsum = 0.f, qs = 0.f, ks = 0.f;
    for (int ch = 0; ch < 64; ch++) {
        const float* base = stats + ((size_t)(b*64 + ch)*8 + h)*288;
        gsum += base[i*16 + j];
        qs   += base[256 + i];
        ks   += base[272 + j];
    }
    float et  = expf(temp[h]);
    float sim = gsum * et / (fmaxf(sqrtf(qs), 1e-12f) * fmaxf(sqrtf(ks), 1e-12f));
    float m = sim;
    #pragma unroll
    for (int d = 1; d < 16; d <<= 1) m = fmaxf(m, __shfl_xor(m, d, 16));
    float e = expf(sim - m);
    float ssum = e;
    #pragma unroll
    for (int d = 1; d < 16; d <<= 1) ssum += __shfl_xor(ssum, d, 16);
    attn[((size_t)(b*8 + h)*16 + i)*16 + j] = e / ssum;
}

// ---------- kernel 4: w_eff[b][o][c] = sum_i w_out[o][h*16+i]*attn[b][h][i][j] ----------
__global__ __launch_bounds__(256) void k_weff(const float* __restrict__ attn,
    const float* __restrict__ wout, bf16_t* __restrict__ weff)
{
    __shared__ float at[2048];
    int bid = blockIdx.x;           // 256 = 8b * 32
    int b = bid >> 5, ob = (bid & 31)*32;
    int t = threadIdx.x;
    #pragma unroll
    for (int r = 0; r < 8; r++) at[t + 256*r] = attn[(size_t)b*2048 + t + 256*r];
    __syncthreads();
    int c = t & 127, h = c >> 4, j = c & 15, oo = (t >> 7)*16;
    #pragma unroll
    for (int m = 0; m < 16; m++) {
        int o = ob + oo + m;
        float acc = 0.f;
        #pragma unroll
        for (int i2 = 0; i2 < 16; i2++)
            acc += wout[(size_t)o*INNER + h*16 + i2] * at[(h*16 + i2)*16 + j];
        weff[((size_t)b*DIM + o)*INNER + c] = (bf16_t)acc;
    }
}

// ---------- kernel 5: output GEMM  per b: (4096x128)x(128x1024), fp32 out ----------
__global__ __launch_bounds__(256) void k_out_gemm(const bf16_t* __restrict__ qkv,
    const bf16_t* __restrict__ weff, float* __restrict__ out)
{
    __shared__ bf16_t Al[128*136];
    __shared__ bf16_t Bl[128*136];
    int bid = blockIdx.x;           // 2048 = 8b * 32mt * 8nt
    int b = bid >> 8, rem = bid & 255;
    int mt = rem >> 3, nt = rem & 7;
    int tok0 = mt*128, o0 = nt*128;
    int t = threadIdx.x;
    #pragma unroll
    for (int rd = 0; rd < 8; rd++) {
        int r  = (t >> 4) + 16*rd;
        int c8 = (t & 15) * 8;
        *reinterpret_cast<uint4*>(&Al[r*136 + c8]) =
            *reinterpret_cast<const uint4*>(
                qkv + ((size_t)b*NTOK + tok0 + r)*QKVC + 256 + c8);   // v cols
        *reinterpret_cast<uint4*>(&Bl[r*136 + c8]) =
            *reinterpret_cast<const uint4*>(
                weff + ((size_t)b*DIM + o0 + r)*INNER + c8);
    }
    __syncthreads();
    int w = t >> 6, lane = t & 63, lr = lane & 15, lg = lane >> 4;
    int wr = (w & 1)*64, wc = (w >> 1)*64;
    f32x4 acc[4][4] = {};
    #pragma unroll
    for (int kk = 0; kk < 4; kk++) {
        int kb = kk*32 + lg*8;
        bf16x8 af[4], bfr[4];
        #pragma unroll
        for (int mi = 0; mi < 4; mi++)
            af[mi] = *reinterpret_cast<const bf16x8*>(&Al[(wr + mi*16 + lr)*136 + kb]);
        #pragma unroll
        for (int ni = 0; ni < 4; ni++)
            bfr[ni] = *reinterpret_cast<const bf16x8*>(&Bl[(wc + ni*16 + lr)*136 + kb]);
        #pragma unroll
        for (int mi = 0; mi < 4; mi++)
            #pragma unroll
            for (int ni = 0; ni < 4; ni++)
                acc[mi][ni] = __builtin_amdgcn_mfma_f32_16x16x32_bf16(
                    af[mi], bfr[ni], acc[mi][ni], 0, 0, 0);
    }
    #pragma unroll
    for (int mi = 0; mi < 4; mi++)
        #pragma unroll
        for (int ni = 0; ni < 4; ni++) {
            int col_g = o0 + wc + ni*16 + lr;
            #pragma unroll
            for (int r = 0; r < 4; r++) {
                int row_g = tok0 + wr + mi*16 + lg*4 + r;
                out[((size_t)b*NTOK + row_g)*DIM + col_g] = acc[mi][ni][r];
            }
        }
}

extern "C" void kernel_launch(void* const* d_in, const int* in_sizes, int n_in,
                              void* d_out, int out_size, void* d_ws, size_t ws_size,
                              hipStream_t stream)
{
    const float* x    = (const float*)d_in[0];   // 8*4096*1024
    const float* nw   = (const float*)d_in[1];   // 1024
    const float* wq   = (const float*)d_in[2];   // 384*1024
    const float* temp = (const float*)d_in[3];   // 8
    const float* wout = (const float*)d_in[4];   // 1024*128
    float* out = (float*)d_out;

    char* ws = (char*)d_ws;
    bf16_t* wqb   = (bf16_t*)(ws + OFF_WQ);
    bf16_t* qkv   = (bf16_t*)(ws + OFF_QKV);
    float*  stats = (float*)(ws + OFF_STATS);
    float*  attn  = (float*)(ws + OFF_ATTN);
    bf16_t* weff  = (bf16_t*)(ws + OFF_WEFF);

    k_wconv    <<<384,  256, 0, stream>>>(wq, nw, wqb);
    k_qkv_gemm <<<768,  256, 0, stream>>>(x, wqb, qkv);
    k_stats    <<<512,  256, 0, stream>>>(qkv, stats);
    k_attn     <<<64,   256, 0, stream>>>(stats, temp, attn);
    k_weff     <<<256,  256, 0, stream>>>(attn, wout, weff);
    k_out_gemm <<<2048, 256, 0, stream>>>(qkv, weff, out);
}